// Round 2
// baseline (112.177 us; speedup 1.0000x reference)
//
#include <hip/hip_runtime.h>
#include <cfloat>
#include <stdint.h>

#define B_ 16
#define N_ 4096
#define M_ 1024
#define EPS_ 1e-12f

typedef float v2f __attribute__((ext_vector_type(2)));

__device__ __forceinline__ v2f fma2(v2f a, v2f b, v2f c) {
    return __builtin_elementwise_fma(a, b, c);     // -> v_pk_fma_f32
}
__device__ __forceinline__ v2f splat(float x) { return (v2f){x, x}; }

__device__ __forceinline__ uint32_t umin3(uint32_t a, uint32_t b, uint32_t c) {
    return min(a, min(b, c));                      // -> v_min3_u32
}
__device__ __forceinline__ uint32_t umed3(uint32_t a, uint32_t b, uint32_t c) {
    return max(min(a, b), min(max(a, b), c));      // -> v_med3_u32
}

// R2: occupancy experiment. Kernel sits ~6x above its VALU/DS/VMEM pipe
// floors at 3 blocks/CU (grid=768 was the binding limit; R1 proved DS is
// not). Phase-split role-1 along the POINT axis: block = (m-chunk 32) x
// (pt-chunk 1024). Staging total is UNCHANGED (4x blocks x 1/4 staging
// each) -- avoids the known "staging duplication" regression. LDS 32->16 KB,
// launch_bounds(256,4) -> 4 blocks/CU. Cross-chunk top-2 merge is NOT
// atomicMin-able, so each block stores its (k1,k2) pair to d_ws (every slot
// written -> no init needed; 512 KB) and a 64-block finalizer merges the 4
// pairs exactly + epilogue. C is computed from the same 32-m set in all 4
// chunks -> bit-identical -> key ordering identical to the old butterfly.
// blocks [0,256):    role 0, cd1 (unchanged; long blocks first).
// blocks [256,2304): role 1, knn partial: b=id>>7, mc=(id&127)>>2, pc=id&3.
__global__ __launch_bounds__(256, 4) void fused_kernel(const float* __restrict__ shape_xyz,
                                                       const float* __restrict__ skel_xyz,
                                                       uint32_t* __restrict__ ws_out,
                                                       float* __restrict__ out)
{
    __shared__ float ls[4096];     // 16 KB: A = ls[0..2047], B = ls[2048..4095]
    __shared__ float ws2[4];

    const int tid = threadIdx.x;
    float4* A4 = (float4*)ls;
    float4* Bq = (float4*)(ls + 2048);

    if (blockIdx.x < 256) {
        // ================= role 0: cd1 (unchanged structure) =================
        const int b    = blockIdx.x >> 4;      // 16 tiles per b
        const int tile = blockIdx.x & 15;

        // skel staging: thread t loads float4 3t..3t+2 = pts 4t..4t+3 = pairs 2t,2t+1
        const float4* g4 = (const float4*)(skel_xyz + (size_t)b * M_ * 3);
        const float4 r0 = g4[3 * tid + 0];
        const float4 r1 = g4[3 * tid + 1];
        const float4 r2 = g4[3 * tid + 2];

        const int sA = tid & 15;
        const int gA = tid >> 4;
        const int n0 = tile * 256 + gA * 16;
        const float* p = shape_xyz + ((size_t)b * N_ + n0) * 6;
        float nx[16], ny[16], nz[16], best[16];
#pragma unroll
        for (int k = 0; k < 16; ++k) {
            nx[k] = -p[k * 6 + 0];
            ny[k] = -p[k * 6 + 1];
            nz[k] = -p[k * 6 + 2];
            best[k] = FLT_MAX;
        }

        {
            const float w0 = fmaf(r0.x, r0.x, fmaf(r0.y, r0.y, r0.z * r0.z));
            const float w1 = fmaf(r0.w, r0.w, fmaf(r1.x, r1.x, r1.y * r1.y));
            const float w2 = fmaf(r1.z, r1.z, fmaf(r1.w, r1.w, r2.x * r2.x));
            const float w3 = fmaf(r2.y, r2.y, fmaf(r2.z, r2.z, r2.w * r2.w));
            A4[2 * tid + 0] = make_float4(2*r0.x, 2*r0.w, 2*r0.y, 2*r1.x);
            Bq[2 * tid + 0] = make_float4(2*r0.z, 2*r1.y, w0, w1);
            A4[2 * tid + 1] = make_float4(2*r1.z, 2*r2.y, 2*r1.w, 2*r2.z);
            Bq[2 * tid + 1] = make_float4(2*r2.x, 2*r2.w, w2, w3);
        }
        __syncthreads();

#pragma unroll 4
        for (int j = 0; j < 32; ++j) {             // pair (2k, 2k+1), k = j*16+sA
            const float4 a = A4[j * 16 + sA];      // -> ds_read_b128, imm offset
            const float4 bq = Bq[j * 16 + sA];
            const v2f sx = {a.x, a.y};
            const v2f sy = {a.z, a.w};
            const v2f sz = {bq.x, bq.y};
            const v2f sw = {bq.z, bq.w};
#pragma unroll
            for (int k = 0; k < 16; ++k) {
                const v2f t = fma2(splat(nx[k]), sx,
                              fma2(splat(ny[k]), sy,
                              fma2(splat(nz[k]), sz, sw)));
                best[k] = fminf(best[k], fminf(t.x, t.y));   // -> v_min3_f32
            }
        }

#pragma unroll
        for (int off = 1; off < 16; off <<= 1) {
#pragma unroll
            for (int k = 0; k < 16; ++k) best[k] = fminf(best[k], __shfl_xor(best[k], off));
        }
        float v = 0.0f;
        if (sA == 0) {
#pragma unroll
            for (int k = 0; k < 16; ++k) {
                const float pp = fmaf(nx[k], nx[k], fmaf(ny[k], ny[k], nz[k] * nz[k]));
                v += sqrtf(fmaxf(best[k] + pp, EPS_));
            }
            v *= 1e-4f;
        }
#pragma unroll
        for (int off = 32; off > 0; off >>= 1) v += __shfl_down(v, off);
        if ((tid & 63) == 0) ws2[tid >> 6] = v;
        __syncthreads();
        if (tid == 0) atomicAdd(out, ws2[0] + ws2[1] + ws2[2] + ws2[3]);
    } else {
        // ================= role 1: knn partial (one pt-chunk) =================
        const int id  = blockIdx.x - 256;
        const int b   = id >> 7;                   // 128 blocks per b
        const int sub = id & 127;
        const int mc  = sub >> 2;                  // m-chunk 0..31 (32 m each)
        const int pc  = sub & 3;                   // pt-chunk 0..3 (1024 pts each)
        const int s   = tid & 63;                  // full-wave j-lane
        const int g   = tid >> 6;                  // wave id 0..3
        const int m0  = mc * 32 + g * 8;           // 8 chains per wave

        float m2x[8], m2y[8], m2z[8], aa[8];
        uint32_t k1[8], k2[8];
        {
            const float* sq = skel_xyz + ((size_t)b * M_ + m0) * 3;
#pragma unroll
            for (int c = 0; c < 8; ++c) {
                const float x = sq[c * 3 + 0];
                const float y = sq[c * 3 + 1];
                const float z = sq[c * 3 + 2];
                m2x[c] = -2.0f * x; m2y[c] = -2.0f * y; m2z[c] = -2.0f * z;
                aa[c]  = fmaf(x, x, fmaf(y, y, z * z));
                k1[c] = 0xFFFFFFFFu; k2[c] = 0xFFFFFFFFu;
            }
        }
        // block-max |m|^2 over the SAME 32-m set in all 4 pt-chunks -> C is
        // bit-identical across chunks -> key order globally consistent.
        float amax = fmaxf(fmaxf(fmaxf(aa[0], aa[1]), fmaxf(aa[2], aa[3])),
                           fmaxf(fmaxf(aa[4], aa[5]), fmaxf(aa[6], aa[7])));
#pragma unroll
        for (int off = 1; off < 64; off <<= 1) amax = fmaxf(amax, __shfl_xor(amax, off));
        if (s == 0) ws2[g] = amax;

        // stage this chunk's 1024 pts: thread t loads float4 6t..6t+5 = pts 4t..4t+3
        const float* sb = shape_xyz + (size_t)b * N_ * 6;
        const float4* g4 = (const float4*)sb;
        float4 r[6];
#pragma unroll
        for (int k = 0; k < 6; ++k) r[k] = g4[pc * 1536 + 6 * tid + k];
        {
            const float4 a0 = r[0], a1 = r[1], a2 = r[2];
            const float4 a3 = r[3], a4 = r[4], a5 = r[5];
            // pts: q0=(a0.x,a0.y,a0.z) q1=(a1.z,a1.w,a2.x) q2=(a3.x,a3.y,a3.z) q3=(a4.z,a4.w,a5.x)
            const float w0 = fmaf(a0.x, a0.x, fmaf(a0.y, a0.y, a0.z * a0.z));
            const float w1 = fmaf(a1.z, a1.z, fmaf(a1.w, a1.w, a2.x * a2.x));
            const float w2 = fmaf(a3.x, a3.x, fmaf(a3.y, a3.y, a3.z * a3.z));
            const float w3 = fmaf(a4.z, a4.z, fmaf(a4.w, a4.w, a5.x * a5.x));
            A4[2 * tid + 0] = make_float4(a0.x, a1.z, a0.y, a1.w);
            Bq[2 * tid + 0] = make_float4(a0.z, a2.x, w0, w1);
            A4[2 * tid + 1] = make_float4(a3.x, a4.z, a3.y, a4.w);
            Bq[2 * tid + 1] = make_float4(a3.z, a5.x, w2, w3);
        }
        __syncthreads();           // ws2 + staging both visible
        const float C = fmaxf(fmaxf(ws2[0], ws2[1]), fmaxf(ws2[2], ws2[3]));
        const uint32_t HI = 0xFFFFF000u;
        const uint32_t nbase = (uint32_t)(pc * 1024 + 2 * s);

#pragma unroll
        for (int j = 0; j < 8; ++j) {              // pair (2k, 2k+1), k = j*64+s
            const float4 a = A4[j * 64 + s];       // -> ds_read_b128, imm offset
            const float4 bq = Bq[j * 64 + s];
            const v2f qx = {a.x, a.y};
            const v2f qy = {a.z, a.w};
            const v2f qz = {bq.x, bq.y};
            const v2f qw0 = {bq.z + C, bq.w + C};
            const uint32_t gn0 = nbase + (uint32_t)(j * 128);
            const uint32_t gn1 = gn0 + 1u;
#pragma unroll
            for (int c = 0; c < 8; ++c) {
                const v2f t = fma2(splat(m2x[c]), qx,
                              fma2(splat(m2y[c]), qy,
                              fma2(splat(m2z[c]), qz, qw0)));
                const uint32_t kk0 = (__float_as_uint(t.x) & HI) | gn0;
                const uint32_t kk1 = (__float_as_uint(t.y) & HI) | gn1;
                k2[c] = min(k2[c], umed3(k1[c], kk0, kk1));
                k1[c] = umin3(k1[c], kk0, kk1);
            }
        }

        // butterfly top-2 merge across the 64 j-lanes of the wave
#pragma unroll
        for (int off = 1; off < 64; off <<= 1) {
#pragma unroll
            for (int c = 0; c < 8; ++c) {
                const uint32_t o1 = (uint32_t)__shfl_xor((int)k1[c], off);
                const uint32_t o2 = (uint32_t)__shfl_xor((int)k2[c], off);
                const uint32_t nk2 = min(min(k2[c], o2), max(k1[c], o1));
                k1[c] = min(k1[c], o1);
                k2[c] = nk2;
            }
        }

        if (s == 0) {
            uint2* w2 = (uint2*)ws_out;            // [b][m][pc] pairs
#pragma unroll
            for (int c = 0; c < 8; ++c)
                w2[(size_t)((b << 10) + m0 + c) * 4 + pc] = make_uint2(k1[c], k2[c]);
        }
    }
}

// finalizer: merge the 4 pt-chunk (k1,k2) pairs per (b,m) exactly, then
// epilogue (exact nearest distance + normal dots) + reduce + atomicAdd.
__global__ __launch_bounds__(256, 8) void finalize_kernel(const float* __restrict__ shape_xyz,
                                                          const float* __restrict__ skel_xyz,
                                                          const float* __restrict__ skel_nori,
                                                          const uint32_t* __restrict__ ws_in,
                                                          float* __restrict__ out)
{
    __shared__ float red[4];
    const int tid = threadIdx.x;
    const int gm  = blockIdx.x * 256 + tid;        // 0..16383  (b = gm>>10, m = gm&1023)
    const int b   = gm >> 10;

    const uint2* w2 = (const uint2*)ws_in;
    uint32_t K1v = 0xFFFFFFFFu, K2v = 0xFFFFFFFFu;
#pragma unroll
    for (int pcn = 0; pcn < 4; ++pcn) {            // top-2 of union of 4 sorted pairs
        const uint2 pr = w2[(size_t)gm * 4 + pcn];
        K2v = min(K2v, umed3(K1v, pr.x, pr.y));
        K1v = umin3(K1v, pr.x, pr.y);
    }

    const float* sb = shape_xyz + (size_t)b * N_ * 6;
    const int i1 = (int)(K1v & 0xFFFu);
    const int i2 = (int)(K2v & 0xFFFu);
    const float* p1 = sb + (size_t)i1 * 6;
    const float* p2 = sb + (size_t)i2 * 6;
    const float* sq = skel_xyz + (size_t)gm * 3;
    const float* no = skel_nori + (size_t)gm * 3;
    const float dx = sq[0] - p1[0], dy = sq[1] - p1[1], dz = sq[2] - p1[2];
    const float d2 = fmaf(dx, dx, fmaf(dy, dy, dz * dz));   // exact (de-quantized)
    const float q0 = no[0], q1 = no[1], q2 = no[2];
    const float dot1 = q0 * p1[3] + q1 * p1[4] + q2 * p1[5];
    const float dot2 = q0 * p2[3] + q1 * p2[4] + q2 * p2[5];
    const float kN = 0.001f * 0.5f / (float)B_;
    float v = sqrtf(fmaxf(d2, EPS_)) * 1e-4f + (fabsf(dot1) + fabsf(dot2)) * kN;

#pragma unroll
    for (int off = 32; off > 0; off >>= 1) v += __shfl_down(v, off);
    if ((tid & 63) == 0) red[tid >> 6] = v;
    __syncthreads();
    if (tid == 0) atomicAdd(out, red[0] + red[1] + red[2] + red[3]);
}

extern "C" void kernel_launch(void* const* d_in, const int* in_sizes, int n_in,
                              void* d_out, int out_size, void* d_ws, size_t ws_size,
                              hipStream_t stream) {
    const float* shape_xyz = (const float*)d_in[0];  // (16, 4096, 6)
    const float* skel_xyz  = (const float*)d_in[1];  // (16, 1024, 3)
    const float* skel_nori = (const float*)d_in[2];  // (16, 1024, 3)
    float* out = (float*)d_out;                      // scalar
    uint32_t* ws = (uint32_t*)d_ws;                  // 512 KB of pair slots

    hipMemsetAsync(out, 0, sizeof(float), stream);   // d_out poisoned each call
    fused_kernel<<<2304, 256, 0, stream>>>(shape_xyz, skel_xyz, ws, out);
    finalize_kernel<<<64, 256, 0, stream>>>(shape_xyz, skel_xyz, skel_nori, ws, out);
}

// Round 3
// 110.965 us; speedup vs baseline: 1.0109x; 1.0109x over previous
//
#include <hip/hip_runtime.h>
#include <cfloat>
#include <stdint.h>

#define B_ 16
#define N_ 4096
#define M_ 1024
#define EPS_ 1e-12f

typedef float v2f __attribute__((ext_vector_type(2)));

__device__ __forceinline__ v2f fma2(v2f a, v2f b, v2f c) {
    return __builtin_elementwise_fma(a, b, c);     // -> v_pk_fma_f32
}
__device__ __forceinline__ v2f splat(float x) { return (v2f){x, x}; }

__device__ __forceinline__ uint32_t umin3(uint32_t a, uint32_t b, uint32_t c) {
    return min(a, min(b, c));                      // -> v_min3_u32
}
__device__ __forceinline__ uint32_t umed3(uint32_t a, uint32_t b, uint32_t c) {
    return max(min(a, b), min(max(a, b), c));      // -> v_med3_u32
}

// R3: R2's point-split structure was sound (passed), but launch_bounds(256,4)
// with only 16.5 KB LDS let the backend aim for 8 waves/EU -> VGPR_Count=64
// -> both roles spilled (~94-100 live regs each). Counters: WRITE_SIZE 44 MB
// (scratch), VALUBusy 28%. Fix: pin amdgpu_waves_per_eu(4,4) -> VGPR budget
// 128, no spills, exactly 4 blocks/CU (vs session-best's 3).
// Decomposition (unchanged from R2):
// blocks [0,256):    role 0, cd1 (16 tiles/b, 256 pts each).
// blocks [256,2304): role 1, knn partial: block = (m-chunk of 32) x
//   (pt-chunk of 1024); b=id>>7, mc=(id&127)>>2, pc=id&3. Total staging per b
//   unchanged (4x blocks x 1/4 staging each). C computed from the same 32-m
//   set in all 4 chunks -> bit-identical -> global key order preserved.
//   Per-(b,m) top-2 pairs stored to d_ws (every slot written, no init);
//   64-block finalizer merges the 4 sorted pairs exactly + epilogue.
__global__ __launch_bounds__(256)
__attribute__((amdgpu_waves_per_eu(4, 4)))
void fused_kernel(const float* __restrict__ shape_xyz,
                  const float* __restrict__ skel_xyz,
                  uint32_t* __restrict__ ws_out,
                  float* __restrict__ out)
{
    __shared__ float ls[4096];     // 16 KB: A = ls[0..2047], B = ls[2048..4095]
    __shared__ float ws2[4];

    const int tid = threadIdx.x;
    float4* A4 = (float4*)ls;
    float4* Bq = (float4*)(ls + 2048);

    if (blockIdx.x < 256) {
        // ================= role 0: cd1 (unchanged structure) =================
        const int b    = blockIdx.x >> 4;      // 16 tiles per b
        const int tile = blockIdx.x & 15;

        // skel staging: thread t loads float4 3t..3t+2 = pts 4t..4t+3 = pairs 2t,2t+1
        const float4* g4 = (const float4*)(skel_xyz + (size_t)b * M_ * 3);
        const float4 r0 = g4[3 * tid + 0];
        const float4 r1 = g4[3 * tid + 1];
        const float4 r2 = g4[3 * tid + 2];

        const int sA = tid & 15;
        const int gA = tid >> 4;
        const int n0 = tile * 256 + gA * 16;
        const float* p = shape_xyz + ((size_t)b * N_ + n0) * 6;
        float nx[16], ny[16], nz[16], best[16];
#pragma unroll
        for (int k = 0; k < 16; ++k) {
            nx[k] = -p[k * 6 + 0];
            ny[k] = -p[k * 6 + 1];
            nz[k] = -p[k * 6 + 2];
            best[k] = FLT_MAX;
        }

        {
            const float w0 = fmaf(r0.x, r0.x, fmaf(r0.y, r0.y, r0.z * r0.z));
            const float w1 = fmaf(r0.w, r0.w, fmaf(r1.x, r1.x, r1.y * r1.y));
            const float w2 = fmaf(r1.z, r1.z, fmaf(r1.w, r1.w, r2.x * r2.x));
            const float w3 = fmaf(r2.y, r2.y, fmaf(r2.z, r2.z, r2.w * r2.w));
            A4[2 * tid + 0] = make_float4(2*r0.x, 2*r0.w, 2*r0.y, 2*r1.x);
            Bq[2 * tid + 0] = make_float4(2*r0.z, 2*r1.y, w0, w1);
            A4[2 * tid + 1] = make_float4(2*r1.z, 2*r2.y, 2*r1.w, 2*r2.z);
            Bq[2 * tid + 1] = make_float4(2*r2.x, 2*r2.w, w2, w3);
        }
        __syncthreads();

#pragma unroll 4
        for (int j = 0; j < 32; ++j) {             // pair (2k, 2k+1), k = j*16+sA
            const float4 a = A4[j * 16 + sA];      // -> ds_read_b128, imm offset
            const float4 bq = Bq[j * 16 + sA];
            const v2f sx = {a.x, a.y};
            const v2f sy = {a.z, a.w};
            const v2f sz = {bq.x, bq.y};
            const v2f sw = {bq.z, bq.w};
#pragma unroll
            for (int k = 0; k < 16; ++k) {
                const v2f t = fma2(splat(nx[k]), sx,
                              fma2(splat(ny[k]), sy,
                              fma2(splat(nz[k]), sz, sw)));
                best[k] = fminf(best[k], fminf(t.x, t.y));   // -> v_min3_f32
            }
        }

#pragma unroll
        for (int off = 1; off < 16; off <<= 1) {
#pragma unroll
            for (int k = 0; k < 16; ++k) best[k] = fminf(best[k], __shfl_xor(best[k], off));
        }
        float v = 0.0f;
        if (sA == 0) {
#pragma unroll
            for (int k = 0; k < 16; ++k) {
                const float pp = fmaf(nx[k], nx[k], fmaf(ny[k], ny[k], nz[k] * nz[k]));
                v += sqrtf(fmaxf(best[k] + pp, EPS_));
            }
            v *= 1e-4f;
        }
#pragma unroll
        for (int off = 32; off > 0; off >>= 1) v += __shfl_down(v, off);
        if ((tid & 63) == 0) ws2[tid >> 6] = v;
        __syncthreads();
        if (tid == 0) atomicAdd(out, ws2[0] + ws2[1] + ws2[2] + ws2[3]);
    } else {
        // ================= role 1: knn partial (one pt-chunk) =================
        const int id  = blockIdx.x - 256;
        const int b   = id >> 7;                   // 128 blocks per b
        const int sub = id & 127;
        const int mc  = sub >> 2;                  // m-chunk 0..31 (32 m each)
        const int pc  = sub & 3;                   // pt-chunk 0..3 (1024 pts each)
        const int s   = tid & 63;                  // full-wave j-lane
        const int g   = tid >> 6;                  // wave id 0..3
        const int m0  = mc * 32 + g * 8;           // 8 chains per wave

        float m2x[8], m2y[8], m2z[8], aa[8];
        uint32_t k1[8], k2[8];
        {
            const float* sq = skel_xyz + ((size_t)b * M_ + m0) * 3;
#pragma unroll
            for (int c = 0; c < 8; ++c) {
                const float x = sq[c * 3 + 0];
                const float y = sq[c * 3 + 1];
                const float z = sq[c * 3 + 2];
                m2x[c] = -2.0f * x; m2y[c] = -2.0f * y; m2z[c] = -2.0f * z;
                aa[c]  = fmaf(x, x, fmaf(y, y, z * z));
                k1[c] = 0xFFFFFFFFu; k2[c] = 0xFFFFFFFFu;
            }
        }
        // block-max |m|^2 over the SAME 32-m set in all 4 pt-chunks -> C is
        // bit-identical across chunks -> key order globally consistent.
        float amax = fmaxf(fmaxf(fmaxf(aa[0], aa[1]), fmaxf(aa[2], aa[3])),
                           fmaxf(fmaxf(aa[4], aa[5]), fmaxf(aa[6], aa[7])));
#pragma unroll
        for (int off = 1; off < 64; off <<= 1) amax = fmaxf(amax, __shfl_xor(amax, off));
        if (s == 0) ws2[g] = amax;

        // stage this chunk's 1024 pts: thread t loads float4 6t..6t+5 = pts 4t..4t+3
        const float* sb = shape_xyz + (size_t)b * N_ * 6;
        const float4* g4 = (const float4*)sb;
        float4 r[6];
#pragma unroll
        for (int k = 0; k < 6; ++k) r[k] = g4[pc * 1536 + 6 * tid + k];
        {
            const float4 a0 = r[0], a1 = r[1], a2 = r[2];
            const float4 a3 = r[3], a4 = r[4], a5 = r[5];
            // pts: q0=(a0.x,a0.y,a0.z) q1=(a1.z,a1.w,a2.x) q2=(a3.x,a3.y,a3.z) q3=(a4.z,a4.w,a5.x)
            const float w0 = fmaf(a0.x, a0.x, fmaf(a0.y, a0.y, a0.z * a0.z));
            const float w1 = fmaf(a1.z, a1.z, fmaf(a1.w, a1.w, a2.x * a2.x));
            const float w2 = fmaf(a3.x, a3.x, fmaf(a3.y, a3.y, a3.z * a3.z));
            const float w3 = fmaf(a4.z, a4.z, fmaf(a4.w, a4.w, a5.x * a5.x));
            A4[2 * tid + 0] = make_float4(a0.x, a1.z, a0.y, a1.w);
            Bq[2 * tid + 0] = make_float4(a0.z, a2.x, w0, w1);
            A4[2 * tid + 1] = make_float4(a3.x, a4.z, a3.y, a4.w);
            Bq[2 * tid + 1] = make_float4(a3.z, a5.x, w2, w3);
        }
        __syncthreads();           // ws2 + staging both visible
        const float C = fmaxf(fmaxf(ws2[0], ws2[1]), fmaxf(ws2[2], ws2[3]));
        const uint32_t HI = 0xFFFFF000u;
        const uint32_t nbase = (uint32_t)(pc * 1024 + 2 * s);

#pragma unroll
        for (int j = 0; j < 8; ++j) {              // pair (2k, 2k+1), k = j*64+s
            const float4 a = A4[j * 64 + s];       // -> ds_read_b128, imm offset
            const float4 bq = Bq[j * 64 + s];
            const v2f qx = {a.x, a.y};
            const v2f qy = {a.z, a.w};
            const v2f qz = {bq.x, bq.y};
            const v2f qw0 = {bq.z + C, bq.w + C};
            const uint32_t gn0 = nbase + (uint32_t)(j * 128);
            const uint32_t gn1 = gn0 + 1u;
#pragma unroll
            for (int c = 0; c < 8; ++c) {
                const v2f t = fma2(splat(m2x[c]), qx,
                              fma2(splat(m2y[c]), qy,
                              fma2(splat(m2z[c]), qz, qw0)));
                const uint32_t kk0 = (__float_as_uint(t.x) & HI) | gn0;
                const uint32_t kk1 = (__float_as_uint(t.y) & HI) | gn1;
                k2[c] = min(k2[c], umed3(k1[c], kk0, kk1));
                k1[c] = umin3(k1[c], kk0, kk1);
            }
        }

        // butterfly top-2 merge across the 64 j-lanes of the wave
#pragma unroll
        for (int off = 1; off < 64; off <<= 1) {
#pragma unroll
            for (int c = 0; c < 8; ++c) {
                const uint32_t o1 = (uint32_t)__shfl_xor((int)k1[c], off);
                const uint32_t o2 = (uint32_t)__shfl_xor((int)k2[c], off);
                const uint32_t nk2 = min(min(k2[c], o2), max(k1[c], o1));
                k1[c] = min(k1[c], o1);
                k2[c] = nk2;
            }
        }

        if (s == 0) {
            uint2* w2 = (uint2*)ws_out;            // [b][m][pc] pairs
#pragma unroll
            for (int c = 0; c < 8; ++c)
                w2[(size_t)((b << 10) + m0 + c) * 4 + pc] = make_uint2(k1[c], k2[c]);
        }
    }
}

// finalizer: merge the 4 pt-chunk (k1,k2) pairs per (b,m) exactly, then
// epilogue (exact nearest distance + normal dots) + reduce + atomicAdd.
__global__ __launch_bounds__(256, 8) void finalize_kernel(const float* __restrict__ shape_xyz,
                                                          const float* __restrict__ skel_xyz,
                                                          const float* __restrict__ skel_nori,
                                                          const uint32_t* __restrict__ ws_in,
                                                          float* __restrict__ out)
{
    __shared__ float red[4];
    const int tid = threadIdx.x;
    const int gm  = blockIdx.x * 256 + tid;        // 0..16383  (b = gm>>10, m = gm&1023)
    const int b   = gm >> 10;

    const uint2* w2 = (const uint2*)ws_in;
    uint32_t K1v = 0xFFFFFFFFu, K2v = 0xFFFFFFFFu;
#pragma unroll
    for (int pcn = 0; pcn < 4; ++pcn) {            // top-2 of union of 4 sorted pairs
        const uint2 pr = w2[(size_t)gm * 4 + pcn];
        K2v = min(K2v, umed3(K1v, pr.x, pr.y));
        K1v = umin3(K1v, pr.x, pr.y);
    }

    const float* sb = shape_xyz + (size_t)b * N_ * 6;
    const int i1 = (int)(K1v & 0xFFFu);
    const int i2 = (int)(K2v & 0xFFFu);
    const float* p1 = sb + (size_t)i1 * 6;
    const float* p2 = sb + (size_t)i2 * 6;
    const float* sq = skel_xyz + (size_t)gm * 3;
    const float* no = skel_nori + (size_t)gm * 3;
    const float dx = sq[0] - p1[0], dy = sq[1] - p1[1], dz = sq[2] - p1[2];
    const float d2 = fmaf(dx, dx, fmaf(dy, dy, dz * dz));   // exact (de-quantized)
    const float q0 = no[0], q1 = no[1], q2 = no[2];
    const float dot1 = q0 * p1[3] + q1 * p1[4] + q2 * p1[5];
    const float dot2 = q0 * p2[3] + q1 * p2[4] + q2 * p2[5];
    const float kN = 0.001f * 0.5f / (float)B_;
    float v = sqrtf(fmaxf(d2, EPS_)) * 1e-4f + (fabsf(dot1) + fabsf(dot2)) * kN;

#pragma unroll
    for (int off = 32; off > 0; off >>= 1) v += __shfl_down(v, off);
    if ((tid & 63) == 0) red[tid >> 6] = v;
    __syncthreads();
    if (tid == 0) atomicAdd(out, red[0] + red[1] + red[2] + red[3]);
}

extern "C" void kernel_launch(void* const* d_in, const int* in_sizes, int n_in,
                              void* d_out, int out_size, void* d_ws, size_t ws_size,
                              hipStream_t stream) {
    const float* shape_xyz = (const float*)d_in[0];  // (16, 4096, 6)
    const float* skel_xyz  = (const float*)d_in[1];  // (16, 1024, 3)
    const float* skel_nori = (const float*)d_in[2];  // (16, 1024, 3)
    float* out = (float*)d_out;                      // scalar
    uint32_t* ws = (uint32_t*)d_ws;                  // 512 KB of pair slots

    hipMemsetAsync(out, 0, sizeof(float), stream);   // d_out poisoned each call
    fused_kernel<<<2304, 256, 0, stream>>>(shape_xyz, skel_xyz, ws, out);
    finalize_kernel<<<64, 256, 0, stream>>>(shape_xyz, skel_xyz, skel_nori, ws, out);
}

// Round 4
// 90.092 us; speedup vs baseline: 1.2451x; 1.2317x over previous
//
#include <hip/hip_runtime.h>
#include <cfloat>
#include <stdint.h>

#define B_ 16
#define N_ 4096
#define M_ 1024
#define EPS_ 1e-12f

typedef float v2f __attribute__((ext_vector_type(2)));

__device__ __forceinline__ v2f fma2(v2f a, v2f b, v2f c) {
    return __builtin_elementwise_fma(a, b, c);     // -> v_pk_fma_f32
}
__device__ __forceinline__ v2f splat(float x) { return (v2f){x, x}; }

__device__ __forceinline__ uint32_t umin3(uint32_t a, uint32_t b, uint32_t c) {
    return min(a, min(b, c));                      // -> v_min3_u32
}
__device__ __forceinline__ uint32_t umed3(uint32_t a, uint32_t b, uint32_t c) {
    return max(min(a, b), min(max(a, b), c));      // -> v_med3_u32
}

// R4: R2/R3 diagnosis complete. VGPR=64 + 44 MB scratch writes in BOTH runs
// -> the allocator's occupancy TARGET comes from LDS-limited occupancy
// (16.9 KB LDS -> 9 blocks/CU -> target 8 waves/EU -> 64 VGPRs -> spill);
// launch_bounds' 2nd arg and amdgpu_waves_per_eu only set a FLOOR, they do
// not lower the target. Baseline (32 KB LDS) compiled to the 4-waves/EU /
// 128-VGPR regime cleanly. Fix: PAD LDS TO 32 KB (16 KB used) -> LDS-limited
// occupancy 4 blocks/CU -> 128-VGPR budget, no spills, 4 resident blocks/CU
// with ~9/CU queued (vs baseline's grid-limited 3).
// Decomposition (unchanged from R2/R3, correctness-proven):
// blocks [0,256):    role 0, cd1 (16 tiles/b, 256 pts each).
// blocks [256,2304): role 1, knn partial: block = (m-chunk of 32) x
//   (pt-chunk of 1024); b=id>>7, mc=(id&127)>>2, pc=id&3. C computed from the
//   same 32-m set in all 4 chunks -> bit-identical -> global key order
//   preserved. Per-(b,m) top-2 pairs stored to d_ws (every slot written, no
//   init); 64-block finalizer merges the 4 sorted pairs exactly + epilogue.
__global__ __launch_bounds__(256)
void fused_kernel(const float* __restrict__ shape_xyz,
                  const float* __restrict__ skel_xyz,
                  uint32_t* __restrict__ ws_out,
                  float* __restrict__ out)
{
    // 32 KB DECLARED, 16 KB used: ls[4096..8191] is a deliberate occupancy
    // shaper (limits to 4 blocks/CU -> allocator targets 4 waves/EU -> 128
    // VGPR budget -> no spills). Do not shrink without re-checking VGPR_Count.
    __shared__ float ls[8192];
    __shared__ float ws2[4];

    const int tid = threadIdx.x;
    float4* A4 = (float4*)ls;
    float4* Bq = (float4*)(ls + 2048);

    if (blockIdx.x < 256) {
        // ================= role 0: cd1 (unchanged structure) =================
        const int b    = blockIdx.x >> 4;      // 16 tiles per b
        const int tile = blockIdx.x & 15;

        // skel staging: thread t loads float4 3t..3t+2 = pts 4t..4t+3 = pairs 2t,2t+1
        const float4* g4 = (const float4*)(skel_xyz + (size_t)b * M_ * 3);
        const float4 r0 = g4[3 * tid + 0];
        const float4 r1 = g4[3 * tid + 1];
        const float4 r2 = g4[3 * tid + 2];

        const int sA = tid & 15;
        const int gA = tid >> 4;
        const int n0 = tile * 256 + gA * 16;
        const float* p = shape_xyz + ((size_t)b * N_ + n0) * 6;
        float nx[16], ny[16], nz[16], best[16];
#pragma unroll
        for (int k = 0; k < 16; ++k) {
            nx[k] = -p[k * 6 + 0];
            ny[k] = -p[k * 6 + 1];
            nz[k] = -p[k * 6 + 2];
            best[k] = FLT_MAX;
        }

        {
            const float w0 = fmaf(r0.x, r0.x, fmaf(r0.y, r0.y, r0.z * r0.z));
            const float w1 = fmaf(r0.w, r0.w, fmaf(r1.x, r1.x, r1.y * r1.y));
            const float w2 = fmaf(r1.z, r1.z, fmaf(r1.w, r1.w, r2.x * r2.x));
            const float w3 = fmaf(r2.y, r2.y, fmaf(r2.z, r2.z, r2.w * r2.w));
            A4[2 * tid + 0] = make_float4(2*r0.x, 2*r0.w, 2*r0.y, 2*r1.x);
            Bq[2 * tid + 0] = make_float4(2*r0.z, 2*r1.y, w0, w1);
            A4[2 * tid + 1] = make_float4(2*r1.z, 2*r2.y, 2*r1.w, 2*r2.z);
            Bq[2 * tid + 1] = make_float4(2*r2.x, 2*r2.w, w2, w3);
        }
        __syncthreads();

#pragma unroll 4
        for (int j = 0; j < 32; ++j) {             // pair (2k, 2k+1), k = j*16+sA
            const float4 a = A4[j * 16 + sA];      // -> ds_read_b128, imm offset
            const float4 bq = Bq[j * 16 + sA];
            const v2f sx = {a.x, a.y};
            const v2f sy = {a.z, a.w};
            const v2f sz = {bq.x, bq.y};
            const v2f sw = {bq.z, bq.w};
#pragma unroll
            for (int k = 0; k < 16; ++k) {
                const v2f t = fma2(splat(nx[k]), sx,
                              fma2(splat(ny[k]), sy,
                              fma2(splat(nz[k]), sz, sw)));
                best[k] = fminf(best[k], fminf(t.x, t.y));   // -> v_min3_f32
            }
        }

#pragma unroll
        for (int off = 1; off < 16; off <<= 1) {
#pragma unroll
            for (int k = 0; k < 16; ++k) best[k] = fminf(best[k], __shfl_xor(best[k], off));
        }
        float v = 0.0f;
        if (sA == 0) {
#pragma unroll
            for (int k = 0; k < 16; ++k) {
                const float pp = fmaf(nx[k], nx[k], fmaf(ny[k], ny[k], nz[k] * nz[k]));
                v += sqrtf(fmaxf(best[k] + pp, EPS_));
            }
            v *= 1e-4f;
        }
#pragma unroll
        for (int off = 32; off > 0; off >>= 1) v += __shfl_down(v, off);
        if ((tid & 63) == 0) ws2[tid >> 6] = v;
        __syncthreads();
        if (tid == 0) atomicAdd(out, ws2[0] + ws2[1] + ws2[2] + ws2[3]);
    } else {
        // ================= role 1: knn partial (one pt-chunk) =================
        const int id  = blockIdx.x - 256;
        const int b   = id >> 7;                   // 128 blocks per b
        const int sub = id & 127;
        const int mc  = sub >> 2;                  // m-chunk 0..31 (32 m each)
        const int pc  = sub & 3;                   // pt-chunk 0..3 (1024 pts each)
        const int s   = tid & 63;                  // full-wave j-lane
        const int g   = tid >> 6;                  // wave id 0..3
        const int m0  = mc * 32 + g * 8;           // 8 chains per wave

        float m2x[8], m2y[8], m2z[8], aa[8];
        uint32_t k1[8], k2[8];
        {
            const float* sq = skel_xyz + ((size_t)b * M_ + m0) * 3;
#pragma unroll
            for (int c = 0; c < 8; ++c) {
                const float x = sq[c * 3 + 0];
                const float y = sq[c * 3 + 1];
                const float z = sq[c * 3 + 2];
                m2x[c] = -2.0f * x; m2y[c] = -2.0f * y; m2z[c] = -2.0f * z;
                aa[c]  = fmaf(x, x, fmaf(y, y, z * z));
                k1[c] = 0xFFFFFFFFu; k2[c] = 0xFFFFFFFFu;
            }
        }
        // block-max |m|^2 over the SAME 32-m set in all 4 pt-chunks -> C is
        // bit-identical across chunks -> key order globally consistent.
        float amax = fmaxf(fmaxf(fmaxf(aa[0], aa[1]), fmaxf(aa[2], aa[3])),
                           fmaxf(fmaxf(aa[4], aa[5]), fmaxf(aa[6], aa[7])));
#pragma unroll
        for (int off = 1; off < 64; off <<= 1) amax = fmaxf(amax, __shfl_xor(amax, off));
        if (s == 0) ws2[g] = amax;

        // stage this chunk's 1024 pts: thread t loads float4 6t..6t+5 = pts 4t..4t+3
        const float* sb = shape_xyz + (size_t)b * N_ * 6;
        const float4* g4 = (const float4*)sb;
        float4 r[6];
#pragma unroll
        for (int k = 0; k < 6; ++k) r[k] = g4[pc * 1536 + 6 * tid + k];
        {
            const float4 a0 = r[0], a1 = r[1], a2 = r[2];
            const float4 a3 = r[3], a4 = r[4], a5 = r[5];
            // pts: q0=(a0.x,a0.y,a0.z) q1=(a1.z,a1.w,a2.x) q2=(a3.x,a3.y,a3.z) q3=(a4.z,a4.w,a5.x)
            const float w0 = fmaf(a0.x, a0.x, fmaf(a0.y, a0.y, a0.z * a0.z));
            const float w1 = fmaf(a1.z, a1.z, fmaf(a1.w, a1.w, a2.x * a2.x));
            const float w2 = fmaf(a3.x, a3.x, fmaf(a3.y, a3.y, a3.z * a3.z));
            const float w3 = fmaf(a4.z, a4.z, fmaf(a4.w, a4.w, a5.x * a5.x));
            A4[2 * tid + 0] = make_float4(a0.x, a1.z, a0.y, a1.w);
            Bq[2 * tid + 0] = make_float4(a0.z, a2.x, w0, w1);
            A4[2 * tid + 1] = make_float4(a3.x, a4.z, a3.y, a4.w);
            Bq[2 * tid + 1] = make_float4(a3.z, a5.x, w2, w3);
        }
        __syncthreads();           // ws2 + staging both visible
        const float C = fmaxf(fmaxf(ws2[0], ws2[1]), fmaxf(ws2[2], ws2[3]));
        const uint32_t HI = 0xFFFFF000u;
        const uint32_t nbase = (uint32_t)(pc * 1024 + 2 * s);

#pragma unroll
        for (int j = 0; j < 8; ++j) {              // pair (2k, 2k+1), k = j*64+s
            const float4 a = A4[j * 64 + s];       // -> ds_read_b128, imm offset
            const float4 bq = Bq[j * 64 + s];
            const v2f qx = {a.x, a.y};
            const v2f qy = {a.z, a.w};
            const v2f qz = {bq.x, bq.y};
            const v2f qw0 = {bq.z + C, bq.w + C};
            const uint32_t gn0 = nbase + (uint32_t)(j * 128);
            const uint32_t gn1 = gn0 + 1u;
#pragma unroll
            for (int c = 0; c < 8; ++c) {
                const v2f t = fma2(splat(m2x[c]), qx,
                              fma2(splat(m2y[c]), qy,
                              fma2(splat(m2z[c]), qz, qw0)));
                const uint32_t kk0 = (__float_as_uint(t.x) & HI) | gn0;
                const uint32_t kk1 = (__float_as_uint(t.y) & HI) | gn1;
                k2[c] = min(k2[c], umed3(k1[c], kk0, kk1));
                k1[c] = umin3(k1[c], kk0, kk1);
            }
        }

        // butterfly top-2 merge across the 64 j-lanes of the wave
#pragma unroll
        for (int off = 1; off < 64; off <<= 1) {
#pragma unroll
            for (int c = 0; c < 8; ++c) {
                const uint32_t o1 = (uint32_t)__shfl_xor((int)k1[c], off);
                const uint32_t o2 = (uint32_t)__shfl_xor((int)k2[c], off);
                const uint32_t nk2 = min(min(k2[c], o2), max(k1[c], o1));
                k1[c] = min(k1[c], o1);
                k2[c] = nk2;
            }
        }

        if (s == 0) {
            uint2* w2 = (uint2*)ws_out;            // [b][m][pc] pairs
#pragma unroll
            for (int c = 0; c < 8; ++c)
                w2[(size_t)((b << 10) + m0 + c) * 4 + pc] = make_uint2(k1[c], k2[c]);
        }
    }
}

// finalizer: merge the 4 pt-chunk (k1,k2) pairs per (b,m) exactly, then
// epilogue (exact nearest distance + normal dots) + reduce + atomicAdd.
__global__ __launch_bounds__(256, 8) void finalize_kernel(const float* __restrict__ shape_xyz,
                                                          const float* __restrict__ skel_xyz,
                                                          const float* __restrict__ skel_nori,
                                                          const uint32_t* __restrict__ ws_in,
                                                          float* __restrict__ out)
{
    __shared__ float red[4];
    const int tid = threadIdx.x;
    const int gm  = blockIdx.x * 256 + tid;        // 0..16383  (b = gm>>10, m = gm&1023)
    const int b   = gm >> 10;

    const uint2* w2 = (const uint2*)ws_in;
    uint32_t K1v = 0xFFFFFFFFu, K2v = 0xFFFFFFFFu;
#pragma unroll
    for (int pcn = 0; pcn < 4; ++pcn) {            // top-2 of union of 4 sorted pairs
        const uint2 pr = w2[(size_t)gm * 4 + pcn];
        K2v = min(K2v, umed3(K1v, pr.x, pr.y));
        K1v = umin3(K1v, pr.x, pr.y);
    }

    const float* sb = shape_xyz + (size_t)b * N_ * 6;
    const int i1 = (int)(K1v & 0xFFFu);
    const int i2 = (int)(K2v & 0xFFFu);
    const float* p1 = sb + (size_t)i1 * 6;
    const float* p2 = sb + (size_t)i2 * 6;
    const float* sq = skel_xyz + (size_t)gm * 3;
    const float* no = skel_nori + (size_t)gm * 3;
    const float dx = sq[0] - p1[0], dy = sq[1] - p1[1], dz = sq[2] - p1[2];
    const float d2 = fmaf(dx, dx, fmaf(dy, dy, dz * dz));   // exact (de-quantized)
    const float q0 = no[0], q1 = no[1], q2 = no[2];
    const float dot1 = q0 * p1[3] + q1 * p1[4] + q2 * p1[5];
    const float dot2 = q0 * p2[3] + q1 * p2[4] + q2 * p2[5];
    const float kN = 0.001f * 0.5f / (float)B_;
    float v = sqrtf(fmaxf(d2, EPS_)) * 1e-4f + (fabsf(dot1) + fabsf(dot2)) * kN;

#pragma unroll
    for (int off = 32; off > 0; off >>= 1) v += __shfl_down(v, off);
    if ((tid & 63) == 0) red[tid >> 6] = v;
    __syncthreads();
    if (tid == 0) atomicAdd(out, red[0] + red[1] + red[2] + red[3]);
}

extern "C" void kernel_launch(void* const* d_in, const int* in_sizes, int n_in,
                              void* d_out, int out_size, void* d_ws, size_t ws_size,
                              hipStream_t stream) {
    const float* shape_xyz = (const float*)d_in[0];  // (16, 4096, 6)
    const float* skel_xyz  = (const float*)d_in[1];  // (16, 1024, 3)
    const float* skel_nori = (const float*)d_in[2];  // (16, 1024, 3)
    float* out = (float*)d_out;                      // scalar
    uint32_t* ws = (uint32_t*)d_ws;                  // 512 KB of pair slots

    hipMemsetAsync(out, 0, sizeof(float), stream);   // d_out poisoned each call
    fused_kernel<<<2304, 256, 0, stream>>>(shape_xyz, skel_xyz, ws, out);
    finalize_kernel<<<64, 256, 0, stream>>>(shape_xyz, skel_xyz, skel_nori, ws, out);
}